// Round 12
// baseline (110.583 us; speedup 1.0000x reference)
//
#include <hip/hip_runtime.h>
#include <hip/hip_bf16.h>
#include <cstdint>

#define TPB 256

constexpr int B = 8, C = 684, H = 64, W = 256;
constexpr int HID = 256, A = 512, K = 11;
constexpr int HW = H * W;      // 16384
constexpr int KK = K * K;      // 121
constexpr int KP = 128;        // padded tap count (K-dim for MFMA)

typedef __attribute__((ext_vector_type(8))) short bf16x8;
typedef __attribute__((ext_vector_type(4))) float f32x4;

__device__ __forceinline__ float fast_tanh(float x) {
    // tanh(x) = 1 - 2/(e^{2x}+1); saturates correctly at +/-inf
    float e = __expf(2.f * x);
    return 1.f - 2.f * __builtin_amdgcn_rcpf(e + 1.f);
}

__device__ __forceinline__ unsigned short f2bf(float f) {
    unsigned u = __float_as_uint(f);
    u += 0x7fffu + ((u >> 16) & 1u);   // RNE
    return (unsigned short)(u >> 16);
}

// Fused: query (blocks 0..15), fw (blocks 16..271), cnt zeroing (block 0)
__global__ void prep_kernel(const float* __restrict__ hidden,
                            const float* __restrict__ W_h,
                            const float* __restrict__ b_h,
                            const float* __restrict__ conv_w,
                            const float* __restrict__ W_att,
                            float* __restrict__ query,
                            unsigned short* __restrict__ fwb,
                            int* __restrict__ cnt) {
    const int bx = blockIdx.x;
    if (bx == 0 && threadIdx.x < B) cnt[threadIdx.x] = 0;   // reset gather counters
    if (bx < 16) {
        // query: hidden[b,k] wave-uniform (s_load); W_h row reads coalesced
        int b = bx >> 1;
        int a = ((bx & 1) << 8) + threadIdx.x;
        float q = b_h[a];
        const float* hb = hidden + b * HID;
        for (int k = 0; k < HID; ++k)
            q = fmaf(hb[k], W_h[k * A + a], q);
        query[b * A + a] = q;
    } else {
        int idx = (bx - 16) * TPB + threadIdx.x;   // A*KP = 65536
        int t = idx >> 9, a = idx & (A - 1);       // t uniform per half-block
        float v = 0.f;
        if (t < KK) {
            for (int ch = 0; ch < 512; ++ch)
                v = fmaf(conv_w[ch * KK + t], W_att[ch * A + a], v);
        }
        fwb[a * KP + t] = f2bf(v);
    }
}

// Implicit-GEMM energy kernel, a-split across 4 blocks of 256 threads.
// Block = (h, az, b): 256 pixels x 128 a. 4 waves, wave owns 32 a.
// OPERAND-SWAPPED MFMA: D = patch * fw  -> C^T layout: lane&15 = a-row,
// (lane>>4)*4+reg = pixel. Fragments are layout-symmetric so pf/fwf reads
// are unchanged; trans reads become per-lane float4 (4x bytes per vmcnt slot).
// VGPR empirics: 512-thread blocks clamp to 64 VGPR (r5/r9 spills);
// 256-thread (256,4) worked (r10 = 101 us, best).
__global__ __launch_bounds__(256, 4) void energy_kernel(
    const float* __restrict__ alpha_sum,
    const float* __restrict__ trans,
    const float* __restrict__ query,
    const unsigned short* __restrict__ fwb,
    const float* __restrict__ W_alpha,
    float* __restrict__ epart) {
    const int h = blockIdx.x, az = blockIdx.y, b = blockIdx.z;
    const int tid = threadIdx.x;
    const int lane = tid & 63, wid = tid >> 6;  // wid 0..3
    const int lg = lane >> 4, lr = lane & 15;   // pixel-group / a-row-in-16
    const int aw = az * 128 + wid * 32;         // wave's a-base

    __shared__ float nb[K][272];                   // 11.7 KB alpha_sum halo
    __shared__ unsigned short patch8[8 * 16 * KP]; // 32 KB: 8 pass-slices
    __shared__ float partAll[4][256];              // 4 KB per-wave partials

    // stage halo: rows h-5..h+5, cols -5..260
    const float* as_b = alpha_sum + b * HW;
    for (int idx = tid; idx < K * 266; idx += 256) {
        int r = idx / 266, j = idx - r * 266;
        int gh = h + r - 5, gw = j - 5;
        float v = 0.f;
        if (gh >= 0 && gh < H && gw >= 0 && gw < W) v = as_b[gh * W + gw];
        nb[r][j] = v;
    }

    // persistent fw B-frags: fw[aw+s*16+lr][ks*32 + lg*8 .. +7]
    bf16x8 fwf[2][4];
#pragma unroll
    for (int s = 0; s < 2; ++s)
#pragma unroll
        for (int ks = 0; ks < 4; ++ks)
            fwf[s][ks] = *(const bf16x8*)(fwb + (aw + s * 16 + lr) * KP + ks * 32 + lg * 8);

    // persistent per-lane q / W_alpha scalars (a = aw + s*16 + lr)
    const float qs0 = query[b * A + aw + lr];
    const float qs1 = query[b * A + aw + 16 + lr];
    const float ws0 = W_alpha[aw + lr];
    const float ws1 = W_alpha[aw + 16 + lr];

    // per-thread build assignment: pixels bp and bp+8, taps btap..btap+3
    const int bp = tid >> 5;              // 0..7
    const int btap = (tid & 31) * 4;      // tap base, multiple of 4
    int boff[4];                          // nb flat offset for pixel bp, -1 if pad
#pragma unroll
    for (int j = 0; j < 4; ++j) {
        int t = btap + j;
        int r = t / K, c = t - r * K;
        boff[j] = (t < KK) ? (r * 272 + bp + c) : -1;
    }
    // (bp+8)&7 == bp&7 -> same XOR term; dst just shifts by 8 rows
    const int bdst = ((bp * KP + btap) ^ ((bp & 7) << 3));  // ushort units
    const int bdst2 = bdst + 8 * KP;

    // per-lane trans row bases (row = a, float4 of 4 consecutive pixels)
    const float* tb = trans + (size_t)b * A * HW + h * W;
    const float* tb0 = tb + (size_t)(aw + lr) * HW;
    const float* tb1 = tb + (size_t)(aw + 16 + lr) * HW;
    const float* nbf = &nb[0][0];
    __syncthreads();

    // prologue: trans for pass 0
    float4 tc0 = *(const float4*)&tb0[lg * 4];
    float4 tc1 = *(const float4*)&tb1[lg * 4];

    for (int half = 0; half < 2; ++half) {
        // ---- build patch for passes half*8 .. half*8+7 (2 px/thread) ----
#pragma unroll
        for (int pp = 0; pp < 8; ++pp) {
            const int p0 = (half * 8 + pp) * 16;
            unsigned short e[4], e2[4];
#pragma unroll
            for (int j = 0; j < 4; ++j) {
                e[j]  = (boff[j] >= 0) ? f2bf(nbf[boff[j] + p0])     : (unsigned short)0;
                e2[j] = (boff[j] >= 0) ? f2bf(nbf[boff[j] + p0 + 8]) : (unsigned short)0;
            }
            uint2 pk, pk2;
            pk.x  = (unsigned)e[0]  | ((unsigned)e[1]  << 16);
            pk.y  = (unsigned)e[2]  | ((unsigned)e[3]  << 16);
            pk2.x = (unsigned)e2[0] | ((unsigned)e2[1] << 16);
            pk2.y = (unsigned)e2[2] | ((unsigned)e2[3] << 16);
            *(uint2*)&patch8[pp * 2048 + bdst]  = pk;
            *(uint2*)&patch8[pp * 2048 + bdst2] = pk2;
        }
        __syncthreads();   // patch slab ready

        // ---- 8 free-running passes (no barriers); tn prefetches pass+1 ----
        for (int pp = 0; pp < 8; ++pp) {
            const int pass = half * 8 + pp;
            const int p0 = pass * 16;
            const int p0n = (pass < 15 ? pass + 1 : pass) * 16;

            // prefetch next pass's trans (float4; consumed next iteration)
            float4 tn0 = *(const float4*)&tb0[p0n + lg * 4];
            float4 tn1 = *(const float4*)&tb1[p0n + lg * 4];

            f32x4 acc[2];
#pragma unroll
            for (int s = 0; s < 2; ++s) acc[s] = (f32x4){0.f, 0.f, 0.f, 0.f};
#pragma unroll
            for (int ks = 0; ks < 4; ++ks) {
                int idx = pp * 2048 + ((lr * KP + ks * 32 + lg * 8) ^ ((lr & 7) << 3));
                bf16x8 pf = *(const bf16x8*)&patch8[idx];
                // swapped operands: A = patch (pixels x taps), B = fw^T
                acc[0] = __builtin_amdgcn_mfma_f32_16x16x32_bf16(pf, fwf[0][ks], acc[0], 0, 0, 0);
                acc[1] = __builtin_amdgcn_mfma_f32_16x16x32_bf16(pf, fwf[1][ks], acc[1], 0, 0, 0);
            }

            // epilogue: x[pixel=lg*4+j][a=aw+s*16+lr]; reduce over a (lr lanes)
            float es[4];
#pragma unroll
            for (int j = 0; j < 4; ++j) {
                float tj0 = (j == 0) ? tc0.x : (j == 1) ? tc0.y : (j == 2) ? tc0.z : tc0.w;
                float tj1 = (j == 0) ? tc1.x : (j == 1) ? tc1.y : (j == 2) ? tc1.z : tc1.w;
                float x0 = acc[0][j] + tj0 + qs0;
                float x1 = acc[1][j] + tj1 + qs1;
                es[j] = fmaf(fast_tanh(x0), ws0, fast_tanh(x1) * ws1);
            }
#pragma unroll
            for (int j = 0; j < 4; ++j) {
                es[j] += __shfl_xor(es[j], 1, 64);
                es[j] += __shfl_xor(es[j], 2, 64);
                es[j] += __shfl_xor(es[j], 4, 64);
                es[j] += __shfl_xor(es[j], 8, 64);
            }
            if (lr == 0) {
#pragma unroll
                for (int j = 0; j < 4; ++j)
                    partAll[wid][p0 + lg * 4 + j] = es[j];   // own slice, no barrier
            }

            tc0 = tn0; tc1 = tn1;
        }
        __syncthreads();   // all reads of patch slab done (and partials visible)
    }

    // ---- final: cross-wave reduce over this block's 128 a -> epart ----
    {
        float e = 0.f;
#pragma unroll
        for (int wv = 0; wv < 4; ++wv) e += partAll[wv][tid];
        epart[(((size_t)b * H + h) * 4 + az) * 256 + tid] = e;
    }
}

// finalize: energy = sum of 4 epart quarters + b_alpha; per-row softmax partials
__global__ void finalize_kernel(const float* __restrict__ epart,
                                const float* __restrict__ b_alpha,
                                const float* __restrict__ mask,
                                float* __restrict__ energy,
                                float* __restrict__ pm,
                                float* __restrict__ ps) {
    const int h = blockIdx.x, b = blockIdx.y;
    const int tid = threadIdx.x;
    const size_t base = ((size_t)b * H + h) * 1024;
    float e = epart[base + tid] + epart[base + 256 + tid] +
              epart[base + 512 + tid] + epart[base + 768 + tid] + b_alpha[0];
    energy[(b * H + h) * W + tid] = e;

    __shared__ float pmw[4], psw[4];
    float s = mask[b * HW + h * W + tid];   // exp(e-e)*mk
    float m = e;
#pragma unroll
    for (int off = 1; off < 64; off <<= 1) {
        float m2 = __shfl_xor(m, off, 64);
        float s2 = __shfl_xor(s, off, 64);
        float nm = fmaxf(m, m2);
        s = s * __expf(m - nm) + s2 * __expf(m2 - nm);
        m = nm;
    }
    if ((tid & 63) == 0) { pmw[tid >> 6] = m; psw[tid >> 6] = s; }
    __syncthreads();
    if (tid == 0) {
        float mm = pmw[0], ss = psw[0];
#pragma unroll
        for (int i = 1; i < 4; ++i) {
            float m2 = pmw[i], s2 = psw[i];
            float nm = fmaxf(mm, m2);
            ss = ss * __expf(mm - nm) + s2 * __expf(m2 - nm);
            mm = nm;
        }
        pm[b * H + h] = mm;
        ps[b * H + h] = ss;
    }
}

// alpha + new_alpha_sum + sparse gather of (alpha > 0.02) pixels.
__global__ void alpha_kernel(const float* __restrict__ energy,
                             const float* __restrict__ mask,
                             const float* __restrict__ alpha_sum,
                             const float* __restrict__ pm,
                             const float* __restrict__ ps,
                             float* __restrict__ out_alpha,
                             float* __restrict__ out_nas,
                             int* __restrict__ cnt,
                             int* __restrict__ gidx,
                             float* __restrict__ gval) {
    const int i4 = blockIdx.x * TPB + threadIdx.x;   // float4 index, B*HW/4 total
    const int b = i4 >> 12;                          // uniform per block
    __shared__ float smax, sinv;
    if (threadIdx.x < 64) {
        float m = pm[b * H + threadIdx.x];
        float s = ps[b * H + threadIdx.x];
#pragma unroll
        for (int off = 32; off > 0; off >>= 1) {
            float m2 = __shfl_xor(m, off, 64);
            float s2 = __shfl_xor(s, off, 64);
            float nm = fmaxf(m, m2);
            s = s * __expf(m - nm) + s2 * __expf(m2 - nm);
            m = nm;
        }
        if (threadIdx.x == 0) { smax = m; sinv = 1.f / (s + 1e-10f); }
    }
    __syncthreads();
    const float mx = smax, iv = sinv;

    float4 ev = ((const float4*)energy)[i4];
    float4 mv = ((const float4*)mask)[i4];
    float4 asv = ((const float4*)alpha_sum)[i4];
    float4 al;
    al.x = __expf(ev.x - mx) * mv.x * iv;
    al.y = __expf(ev.y - mx) * mv.y * iv;
    al.z = __expf(ev.z - mx) * mv.z * iv;
    al.w = __expf(ev.w - mx) * mv.w * iv;
    ((float4*)out_alpha)[i4] = al;
    float4 nv;
    nv.x = al.x + asv.x; nv.y = al.y + asv.y;
    nv.z = al.z + asv.z; nv.w = al.w + asv.w;
    ((float4*)out_nas)[i4] = nv;

    // sparse gather (expected: ~0 passing pixels for softmax over 16K)
    const int p0 = (i4 << 2) & (HW - 1);
#pragma unroll
    for (int j = 0; j < 4; ++j) {
        float a = (j == 0) ? al.x : (j == 1) ? al.y : (j == 2) ? al.z : al.w;
        if (a > 0.02f) {
            int slot = atomicAdd(&cnt[b], 1);
            gidx[b * HW + slot] = p0 + j;
            gval[b * HW + slot] = a;
        }
    }
}

// context[b,c] = sum over gathered pixels: gval * feat[b,c,gidx]
__global__ void context_kernel(const float* __restrict__ feat,
                               const int* __restrict__ cnt,
                               const int* __restrict__ gidx,
                               const float* __restrict__ gval,
                               float* __restrict__ out_ctx) {
    const int c = blockIdx.x, b = blockIdx.y;
    const int n = cnt[b];
    const float* fb = feat + ((size_t)b * C + c) * HW;
    float s = 0.f;
    for (int k = threadIdx.x; k < n; k += 64)
        s += gval[b * HW + k] * fb[gidx[b * HW + k]];
#pragma unroll
    for (int off = 32; off > 0; off >>= 1) s += __shfl_down(s, off, 64);
    if (threadIdx.x == 0) out_ctx[b * C + c] = s;
}

extern "C" void kernel_launch(void* const* d_in, const int* in_sizes, int n_in,
                              void* d_out, int out_size, void* d_ws, size_t ws_size,
                              hipStream_t stream) {
    const float* cnn_features = (const float*)d_in[0];
    const float* trans        = (const float*)d_in[1];
    const float* hidden       = (const float*)d_in[2];
    const float* alpha_sum    = (const float*)d_in[3];
    const float* image_mask   = (const float*)d_in[4];
    const float* W_h          = (const float*)d_in[5];
    const float* b_h          = (const float*)d_in[6];
    const float* conv_w       = (const float*)d_in[7];
    const float* W_att        = (const float*)d_in[8];
    const float* W_alpha      = (const float*)d_in[9];
    const float* b_alpha      = (const float*)d_in[10];

    float* out       = (float*)d_out;
    float* out_ctx   = out;               // B*C
    float* out_alpha = out + B * C;       // B*HW
    float* out_nas   = out_alpha + B * HW;

    float* ws = (float*)d_ws;
    float*          query  = ws;                           // 4096 f
    unsigned short* fwb    = (unsigned short*)(ws + 4096); // 65536 ushort
    float*          energy = ws + 4096 + 32768;            // 131072 f
    float*          pm     = energy + B * HW;              // 512
    float*          ps     = pm + B * H;                   // 512
    int*            cnt    = (int*)(ps + B * H);           // 8
    int*            gidx   = cnt + 8;                      // B*HW
    float*          gval   = (float*)(gidx + B * HW);      // B*HW
    float*          epart  = gval + B * HW;                // B*H*4*256 = 524288 f

    hipLaunchKernelGGL(prep_kernel, dim3(16 + (A * KP) / TPB), dim3(TPB), 0, stream,
                       hidden, W_h, b_h, conv_w, W_att, query, fwb, cnt);
    hipLaunchKernelGGL(energy_kernel, dim3(H, 4, B), dim3(256), 0, stream,
                       alpha_sum, trans, query, fwb, W_alpha, epart);
    hipLaunchKernelGGL(finalize_kernel, dim3(H, B), dim3(TPB), 0, stream,
                       epart, b_alpha, image_mask, energy, pm, ps);
    hipLaunchKernelGGL(alpha_kernel, dim3(B * HW / (TPB * 4)), dim3(TPB), 0, stream,
                       energy, image_mask, alpha_sum, pm, ps,
                       out_alpha, out_nas, cnt, gidx, gval);
    hipLaunchKernelGGL(context_kernel, dim3(C, B), dim3(64), 0, stream,
                       cnn_features, cnt, gidx, gval, out_ctx);
}

// Round 13
// 101.707 us; speedup vs baseline: 1.0873x; 1.0873x over previous
//
#include <hip/hip_runtime.h>
#include <hip/hip_bf16.h>
#include <cstdint>

#define TPB 256

constexpr int B = 8, C = 684, H = 64, W = 256;
constexpr int HID = 256, A = 512, K = 11;
constexpr int HW = H * W;      // 16384
constexpr int KK = K * K;      // 121
constexpr int KP = 128;        // padded tap count (K-dim for MFMA)

typedef __attribute__((ext_vector_type(8))) short bf16x8;
typedef __attribute__((ext_vector_type(4))) float f32x4;

__device__ __forceinline__ float fast_tanh(float x) {
    // tanh(x) = 1 - 2/(e^{2x}+1); saturates correctly at +/-inf
    float e = __expf(2.f * x);
    return 1.f - 2.f * __builtin_amdgcn_rcpf(e + 1.f);
}

__device__ __forceinline__ unsigned short f2bf(float f) {
    unsigned u = __float_as_uint(f);
    u += 0x7fffu + ((u >> 16) & 1u);   // RNE
    return (unsigned short)(u >> 16);
}

// Fused: query (blocks 0..15), fw (blocks 16..271), cnt zeroing (block 0)
__global__ void prep_kernel(const float* __restrict__ hidden,
                            const float* __restrict__ W_h,
                            const float* __restrict__ b_h,
                            const float* __restrict__ conv_w,
                            const float* __restrict__ W_att,
                            float* __restrict__ query,
                            unsigned short* __restrict__ fwb,
                            int* __restrict__ cnt) {
    const int bx = blockIdx.x;
    if (bx == 0 && threadIdx.x < B) cnt[threadIdx.x] = 0;   // reset gather counters
    if (bx < 16) {
        // query: hidden[b,k] wave-uniform (s_load); W_h row reads coalesced
        int b = bx >> 1;
        int a = ((bx & 1) << 8) + threadIdx.x;
        float q = b_h[a];
        const float* hb = hidden + b * HID;
        for (int k = 0; k < HID; ++k)
            q = fmaf(hb[k], W_h[k * A + a], q);
        query[b * A + a] = q;
    } else {
        int idx = (bx - 16) * TPB + threadIdx.x;   // A*KP = 65536
        int t = idx >> 9, a = idx & (A - 1);       // t uniform per half-block
        float v = 0.f;
        if (t < KK) {
            for (int ch = 0; ch < 512; ++ch)
                v = fmaf(conv_w[ch * KK + t], W_att[ch * A + a], v);
        }
        fwb[a * KP + t] = f2bf(v);
    }
}

// Implicit-GEMM energy kernel, a-split across 4 blocks of 256 threads.
// Block = (h, az, b): 256 pixels x 128 a. 4 waves, wave owns 32 a.
// MFMA 16x16x32 bf16: A = fw (a x taps), B = im2col patch (taps x pixels).
// C layout (m89-verified): col = lane&15 = pixel, row = (lane>>4)*4+reg = a-offset.
// BEST CONFIG (r10 = 101.46 us). Perturbations tried and rejected:
//  - 512-thread blocks: VGPR clamp to 64 -> spill disaster (r5/r9)
//  - 4-pass slab for 4 blocks/CU TLP: neutral-negative (r11, 105.6)
//  - operand-swapped MFMA + float4 trans loads: negative (r12, 110.6)
//  - barrier-minimized free-run: neutral (r7)
__global__ __launch_bounds__(256, 4) void energy_kernel(
    const float* __restrict__ alpha_sum,
    const float* __restrict__ trans,
    const float* __restrict__ query,
    const unsigned short* __restrict__ fwb,
    const float* __restrict__ W_alpha,
    float* __restrict__ epart) {
    const int h = blockIdx.x, az = blockIdx.y, b = blockIdx.z;
    const int tid = threadIdx.x;
    const int lane = tid & 63, wid = tid >> 6;  // wid 0..3
    const int lg = lane >> 4, lr = lane & 15;   // k-group, row-in-16
    const int aw = az * 128 + wid * 32;         // wave's a-base

    __shared__ float nb[K][272];                   // 11.7 KB alpha_sum halo
    __shared__ unsigned short patch8[8 * 16 * KP]; // 32 KB: 8 pass-slices
    __shared__ float partAll[4][256];              // 4 KB per-wave partials

    // stage halo: rows h-5..h+5, cols -5..260
    const float* as_b = alpha_sum + b * HW;
    for (int idx = tid; idx < K * 266; idx += 256) {
        int r = idx / 266, j = idx - r * 266;
        int gh = h + r - 5, gw = j - 5;
        float v = 0.f;
        if (gh >= 0 && gh < H && gw >= 0 && gw < W) v = as_b[gh * W + gw];
        nb[r][j] = v;
    }

    // persistent fw A-frags: fw[aw+s*16+lr][ks*32 + lg*8 .. +7]
    bf16x8 fwf[2][4];
#pragma unroll
    for (int s = 0; s < 2; ++s)
#pragma unroll
        for (int ks = 0; ks < 4; ++ks)
            fwf[s][ks] = *(const bf16x8*)(fwb + (aw + s * 16 + lr) * KP + ks * 32 + lg * 8);

    // per-thread build assignment: pixels bp and bp+8, taps btap..btap+3
    const int bp = tid >> 5;              // 0..7
    const int btap = (tid & 31) * 4;      // tap base, multiple of 4
    int boff[4];                          // nb flat offset for pixel bp, -1 if pad
#pragma unroll
    for (int j = 0; j < 4; ++j) {
        int t = btap + j;
        int r = t / K, c = t - r * K;
        boff[j] = (t < KK) ? (r * 272 + bp + c) : -1;
    }
    // (bp+8)&7 == bp&7 -> same XOR term; dst just shifts by 8 rows
    const int bdst = ((bp * KP + btap) ^ ((bp & 7) << 3));  // ushort units
    const int bdst2 = bdst + 8 * KP;

    const float4* q4 = (const float4*)(query + b * A + aw);   // L1-resident
    const float4* w4 = (const float4*)(W_alpha + aw);         // L1-resident
    const float* tb = trans + (size_t)b * A * HW + h * W;
    const float* nbf = &nb[0][0];
    __syncthreads();

    // prologue: trans for pass 0
    float tc[2][4];
#pragma unroll
    for (int s = 0; s < 2; ++s)
#pragma unroll
        for (int j = 0; j < 4; ++j)
            tc[s][j] = tb[(size_t)(aw + s * 16 + lg * 4 + j) * HW + lr];

    for (int half = 0; half < 2; ++half) {
        // ---- build patch for passes half*8 .. half*8+7 (2 pixels/thread) ----
#pragma unroll
        for (int pp = 0; pp < 8; ++pp) {
            const int p0 = (half * 8 + pp) * 16;
            unsigned short e[4], e2[4];
#pragma unroll
            for (int j = 0; j < 4; ++j) {
                e[j]  = (boff[j] >= 0) ? f2bf(nbf[boff[j] + p0])     : (unsigned short)0;
                e2[j] = (boff[j] >= 0) ? f2bf(nbf[boff[j] + p0 + 8]) : (unsigned short)0;
            }
            uint2 pk, pk2;
            pk.x  = (unsigned)e[0]  | ((unsigned)e[1]  << 16);
            pk.y  = (unsigned)e[2]  | ((unsigned)e[3]  << 16);
            pk2.x = (unsigned)e2[0] | ((unsigned)e2[1] << 16);
            pk2.y = (unsigned)e2[2] | ((unsigned)e2[3] << 16);
            *(uint2*)&patch8[pp * 2048 + bdst]  = pk;
            *(uint2*)&patch8[pp * 2048 + bdst2] = pk2;
        }
        __syncthreads();   // patch slab ready

        // ---- 8 free-running passes (no barriers); tn prefetches pass+1 ----
        for (int pp = 0; pp < 8; ++pp) {
            const int pass = half * 8 + pp;
            const int p0 = pass * 16;
            const int p0n = (pass < 15 ? pass + 1 : pass) * 16;

            // prefetch next pass's trans (consumed next iteration)
            float tn[2][4];
#pragma unroll
            for (int s = 0; s < 2; ++s)
#pragma unroll
                for (int j = 0; j < 4; ++j)
                    tn[s][j] = tb[(size_t)(aw + s * 16 + lg * 4 + j) * HW + p0n + lr];

            f32x4 acc[2];
#pragma unroll
            for (int s = 0; s < 2; ++s) acc[s] = (f32x4){0.f, 0.f, 0.f, 0.f};
#pragma unroll
            for (int ks = 0; ks < 4; ++ks) {
                int idx = pp * 2048 + ((lr * KP + ks * 32 + lg * 8) ^ ((lr & 7) << 3));
                bf16x8 pf = *(const bf16x8*)&patch8[idx];
#pragma unroll
                for (int s = 0; s < 2; ++s)
                    acc[s] = __builtin_amdgcn_mfma_f32_16x16x32_bf16(fwf[s][ks], pf, acc[s], 0, 0, 0);
            }

            // epilogue: tanh(cov + q + trans) * w_alpha, reduce over a
            float es = 0.f;
#pragma unroll
            for (int s = 0; s < 2; ++s) {
                float4 qv = q4[s * 4 + lg];
                float4 wv = w4[s * 4 + lg];
#pragma unroll
                for (int j = 0; j < 4; ++j) {
                    float qj = (j == 0) ? qv.x : (j == 1) ? qv.y : (j == 2) ? qv.z : qv.w;
                    float wj = (j == 0) ? wv.x : (j == 1) ? wv.y : (j == 2) ? wv.z : wv.w;
                    float x = acc[s][j] + tc[s][j] + qj;
                    es = fmaf(fast_tanh(x), wj, es);
                }
            }
            // lanes {l, l^16, l^32, l^48} share pixel lr -> reduce over a-groups
            es += __shfl_xor(es, 16, 64);
            es += __shfl_xor(es, 32, 64);
            if (lane < 16) partAll[wid][p0 + lane] = es;   // own slice, no barrier

#pragma unroll
            for (int s = 0; s < 2; ++s)
#pragma unroll
                for (int j = 0; j < 4; ++j)
                    tc[s][j] = tn[s][j];
        }
        __syncthreads();   // all reads of patch slab done (and partials visible)
    }

    // ---- final: cross-wave reduce over this block's 128 a -> epart ----
    {
        float e = 0.f;
#pragma unroll
        for (int wv = 0; wv < 4; ++wv) e += partAll[wv][tid];
        epart[(((size_t)b * H + h) * 4 + az) * 256 + tid] = e;
    }
}

// finalize: energy = sum of 4 epart quarters + b_alpha; per-row softmax partials
__global__ void finalize_kernel(const float* __restrict__ epart,
                                const float* __restrict__ b_alpha,
                                const float* __restrict__ mask,
                                float* __restrict__ energy,
                                float* __restrict__ pm,
                                float* __restrict__ ps) {
    const int h = blockIdx.x, b = blockIdx.y;
    const int tid = threadIdx.x;
    const size_t base = ((size_t)b * H + h) * 1024;
    float e = epart[base + tid] + epart[base + 256 + tid] +
              epart[base + 512 + tid] + epart[base + 768 + tid] + b_alpha[0];
    energy[(b * H + h) * W + tid] = e;

    __shared__ float pmw[4], psw[4];
    float s = mask[b * HW + h * W + tid];   // exp(e-e)*mk
    float m = e;
#pragma unroll
    for (int off = 1; off < 64; off <<= 1) {
        float m2 = __shfl_xor(m, off, 64);
        float s2 = __shfl_xor(s, off, 64);
        float nm = fmaxf(m, m2);
        s = s * __expf(m - nm) + s2 * __expf(m2 - nm);
        m = nm;
    }
    if ((tid & 63) == 0) { pmw[tid >> 6] = m; psw[tid >> 6] = s; }
    __syncthreads();
    if (tid == 0) {
        float mm = pmw[0], ss = psw[0];
#pragma unroll
        for (int i = 1; i < 4; ++i) {
            float m2 = pmw[i], s2 = psw[i];
            float nm = fmaxf(mm, m2);
            ss = ss * __expf(mm - nm) + s2 * __expf(m2 - nm);
            mm = nm;
        }
        pm[b * H + h] = mm;
        ps[b * H + h] = ss;
    }
}

// alpha + new_alpha_sum + sparse gather of (alpha > 0.02) pixels.
__global__ void alpha_kernel(const float* __restrict__ energy,
                             const float* __restrict__ mask,
                             const float* __restrict__ alpha_sum,
                             const float* __restrict__ pm,
                             const float* __restrict__ ps,
                             float* __restrict__ out_alpha,
                             float* __restrict__ out_nas,
                             int* __restrict__ cnt,
                             int* __restrict__ gidx,
                             float* __restrict__ gval) {
    const int i4 = blockIdx.x * TPB + threadIdx.x;   // float4 index, B*HW/4 total
    const int b = i4 >> 12;                          // uniform per block
    __shared__ float smax, sinv;
    if (threadIdx.x < 64) {
        float m = pm[b * H + threadIdx.x];
        float s = ps[b * H + threadIdx.x];
#pragma unroll
        for (int off = 32; off > 0; off >>= 1) {
            float m2 = __shfl_xor(m, off, 64);
            float s2 = __shfl_xor(s, off, 64);
            float nm = fmaxf(m, m2);
            s = s * __expf(m - nm) + s2 * __expf(m2 - nm);
            m = nm;
        }
        if (threadIdx.x == 0) { smax = m; sinv = 1.f / (s + 1e-10f); }
    }
    __syncthreads();
    const float mx = smax, iv = sinv;

    float4 ev = ((const float4*)energy)[i4];
    float4 mv = ((const float4*)mask)[i4];
    float4 asv = ((const float4*)alpha_sum)[i4];
    float4 al;
    al.x = __expf(ev.x - mx) * mv.x * iv;
    al.y = __expf(ev.y - mx) * mv.y * iv;
    al.z = __expf(ev.z - mx) * mv.z * iv;
    al.w = __expf(ev.w - mx) * mv.w * iv;
    ((float4*)out_alpha)[i4] = al;
    float4 nv;
    nv.x = al.x + asv.x; nv.y = al.y + asv.y;
    nv.z = al.z + asv.z; nv.w = al.w + asv.w;
    ((float4*)out_nas)[i4] = nv;

    // sparse gather (expected: ~0 passing pixels for softmax over 16K)
    const int p0 = (i4 << 2) & (HW - 1);
#pragma unroll
    for (int j = 0; j < 4; ++j) {
        float a = (j == 0) ? al.x : (j == 1) ? al.y : (j == 2) ? al.z : al.w;
        if (a > 0.02f) {
            int slot = atomicAdd(&cnt[b], 1);
            gidx[b * HW + slot] = p0 + j;
            gval[b * HW + slot] = a;
        }
    }
}

// context[b,c] = sum over gathered pixels: gval * feat[b,c,gidx]
__global__ void context_kernel(const float* __restrict__ feat,
                               const int* __restrict__ cnt,
                               const int* __restrict__ gidx,
                               const float* __restrict__ gval,
                               float* __restrict__ out_ctx) {
    const int c = blockIdx.x, b = blockIdx.y;
    const int n = cnt[b];
    const float* fb = feat + ((size_t)b * C + c) * HW;
    float s = 0.f;
    for (int k = threadIdx.x; k < n; k += 64)
        s += gval[b * HW + k] * fb[gidx[b * HW + k]];
#pragma unroll
    for (int off = 32; off > 0; off >>= 1) s += __shfl_down(s, off, 64);
    if (threadIdx.x == 0) out_ctx[b * C + c] = s;
}

extern "C" void kernel_launch(void* const* d_in, const int* in_sizes, int n_in,
                              void* d_out, int out_size, void* d_ws, size_t ws_size,
                              hipStream_t stream) {
    const float* cnn_features = (const float*)d_in[0];
    const float* trans        = (const float*)d_in[1];
    const float* hidden       = (const float*)d_in[2];
    const float* alpha_sum    = (const float*)d_in[3];
    const float* image_mask   = (const float*)d_in[4];
    const float* W_h          = (const float*)d_in[5];
    const float* b_h          = (const float*)d_in[6];
    const float* conv_w       = (const float*)d_in[7];
    const float* W_att        = (const float*)d_in[8];
    const float* W_alpha      = (const float*)d_in[9];
    const float* b_alpha      = (const float*)d_in[10];

    float* out       = (float*)d_out;
    float* out_ctx   = out;               // B*C
    float* out_alpha = out + B * C;       // B*HW
    float* out_nas   = out_alpha + B * HW;

    float* ws = (float*)d_ws;
    float*          query  = ws;                           // 4096 f
    unsigned short* fwb    = (unsigned short*)(ws + 4096); // 65536 ushort
    float*          energy = ws + 4096 + 32768;            // 131072 f
    float*          pm     = energy + B * HW;              // 512
    float*          ps     = pm + B * H;                   // 512
    int*            cnt    = (int*)(ps + B * H);           // 8
    int*            gidx   = cnt + 8;                      // B*HW
    float*          gval   = (float*)(gidx + B * HW);      // B*HW
    float*          epart  = gval + B * HW;                // B*H*4*256 = 524288 f

    hipLaunchKernelGGL(prep_kernel, dim3(16 + (A * KP) / TPB), dim3(TPB), 0, stream,
                       hidden, W_h, b_h, conv_w, W_att, query, fwb, cnt);
    hipLaunchKernelGGL(energy_kernel, dim3(H, 4, B), dim3(256), 0, stream,
                       alpha_sum, trans, query, fwb, W_alpha, epart);
    hipLaunchKernelGGL(finalize_kernel, dim3(H, B), dim3(TPB), 0, stream,
                       epart, b_alpha, image_mask, energy, pm, ps);
    hipLaunchKernelGGL(alpha_kernel, dim3(B * HW / (TPB * 4)), dim3(TPB), 0, stream,
                       energy, image_mask, alpha_sum, pm, ps,
                       out_alpha, out_nas, cnt, gidx, gval);
    hipLaunchKernelGGL(context_kernel, dim3(C, B), dim3(64), 0, stream,
                       cnn_features, cnt, gidx, gval, out_ctx);
}